// Round 1
// baseline (20869.498 us; speedup 1.0000x reference)
//
#include <hip/hip_runtime.h>
#include <cstdint>

#define DEVI __device__ __forceinline__

typedef unsigned short ushort_t;
typedef __attribute__((ext_vector_type(8))) short s16x8;
typedef __attribute__((ext_vector_type(4))) float f32x4;

DEVI ushort_t f2bf(float f) {
  uint32_t u = __builtin_bit_cast(uint32_t, f);
  u += 0x7fffu + ((u >> 16) & 1u);
  return (ushort_t)(u >> 16);
}
DEVI float bf2f(ushort_t u) {
  uint32_t x = ((uint32_t)u) << 16;
  return __builtin_bit_cast(float, x);
}
DEVI float sigmoidf_(float x) { return 1.0f / (1.0f + __expf(-x)); }
DEVI float tanhf_(float x) {
  float e = __expf(-2.0f * fabsf(x));
  float r = (1.0f - e) / (1.0f + e);
  return copysignf(r, x);
}

// ---------------- cast f32 -> bf16 (vectorized x8) ----------------
__global__ void cast_kernel(const float* __restrict__ in, ushort_t* __restrict__ out, long n) {
  long i = ((long)blockIdx.x * blockDim.x + threadIdx.x) * 8;
  if (i >= n) return;
  float4 a = *(const float4*)(in + i);
  float4 b = *(const float4*)(in + i + 4);
  union { s16x8 v; ushort_t u[8]; } r;
  r.u[0] = f2bf(a.x); r.u[1] = f2bf(a.y); r.u[2] = f2bf(a.z); r.u[3] = f2bf(a.w);
  r.u[4] = f2bf(b.x); r.u[5] = f2bf(b.y); r.u[6] = f2bf(b.z); r.u[7] = f2bf(b.w);
  *(s16x8*)(out + i) = r.v;
}

// ---------------- 512x512 f32 transpose ----------------
__global__ void transpose512(const float* __restrict__ in, float* __restrict__ out) {
  __shared__ float tile[32][33];
  int bx = blockIdx.x * 32, by = blockIdx.y * 32;
  int tx = threadIdx.x, ty = threadIdx.y;  // 32x8
  for (int i = 0; i < 32; i += 8)
    tile[ty + i][tx] = in[(by + ty + i) * 512 + bx + tx];
  __syncthreads();
  for (int i = 0; i < 32; i += 8)
    out[(bx + ty + i) * 512 + by + tx] = tile[tx][ty + i];
}

// ---------------- bf16 GEMM: C[m,n] = sum_k A[m,k]*B[n,k] + bias ----------------
// BM=BN=128, BK=64, 4 waves (2x2), 16x16x32 MFMA, XOR-swizzled LDS, reg-staged dbuf.
__global__ __launch_bounds__(256, 2)
void gemm_bt(const ushort_t* __restrict__ A, const ushort_t* __restrict__ B,
             const float* __restrict__ bias0, const float* __restrict__ bias1,
             ushort_t* __restrict__ C, int N, int K) {
  __shared__ __align__(16) ushort_t As[128 * 64];
  __shared__ __align__(16) ushort_t Bs[128 * 64];
  const int tid = threadIdx.x;
  const int lane = tid & 63, wv = tid >> 6;
  const int wm = wv >> 1, wn = wv & 1;
  const int l15 = lane & 15, l4 = lane >> 4;
  const long m0 = (long)blockIdx.x * 128;
  const int n0 = blockIdx.y * 128;
  const int nkt = K / 64;

  f32x4 acc[4][4] = {};

  int soff[4];
#pragma unroll
  for (int i = 0; i < 4; ++i) {
    int c = tid + i * 256;
    int r = c >> 3, ks = c & 7;
    soff[i] = r * 64 + ((ks ^ (r & 7)) << 3);
  }

  // prologue: stage kt=0
#pragma unroll
  for (int i = 0; i < 4; ++i) {
    int c = tid + i * 256; int r = c >> 3; int ks = c & 7;
    *(s16x8*)&As[soff[i]] = *(const s16x8*)&A[(m0 + r) * K + ks * 8];
    *(s16x8*)&Bs[soff[i]] = *(const s16x8*)&B[(long)(n0 + r) * K + ks * 8];
  }
  __syncthreads();

  for (int kt = 0; kt < nkt; ++kt) {
    s16x8 ra[4], rb[4];
    const bool more = (kt + 1 < nkt);
    if (more) {
      const long kb = (long)(kt + 1) * 64;
#pragma unroll
      for (int i = 0; i < 4; ++i) {
        int c = tid + i * 256; int r = c >> 3; int ks = c & 7;
        ra[i] = *(const s16x8*)&A[(m0 + r) * K + kb + ks * 8];
        rb[i] = *(const s16x8*)&B[(long)(n0 + r) * K + kb + ks * 8];
      }
    }
#pragma unroll
    for (int kk = 0; kk < 2; ++kk) {
      s16x8 af[4], bfv[4];
      int slot = kk * 4 + l4;
#pragma unroll
      for (int i = 0; i < 4; ++i) {
        int rA = wm * 64 + i * 16 + l15;
        af[i] = *(const s16x8*)&As[rA * 64 + ((slot ^ (rA & 7)) << 3)];
        int rB = wn * 64 + i * 16 + l15;
        bfv[i] = *(const s16x8*)&Bs[rB * 64 + ((slot ^ (rB & 7)) << 3)];
      }
#pragma unroll
      for (int i = 0; i < 4; ++i)
#pragma unroll
        for (int j = 0; j < 4; ++j)
          acc[i][j] = __builtin_amdgcn_mfma_f32_16x16x32_bf16(af[i], bfv[j], acc[i][j], 0, 0, 0);
    }
    __syncthreads();
    if (more) {
#pragma unroll
      for (int i = 0; i < 4; ++i) {
        *(s16x8*)&As[soff[i]] = ra[i];
        *(s16x8*)&Bs[soff[i]] = rb[i];
      }
      __syncthreads();
    }
  }
  // epilogue: D mapping col=lane&15, row=(lane>>4)*4+r
#pragma unroll
  for (int i = 0; i < 4; ++i) {
#pragma unroll
    for (int j = 0; j < 4; ++j) {
#pragma unroll
      for (int r = 0; r < 4; ++r) {
        long m = m0 + wm * 64 + i * 16 + l4 * 4 + r;
        int n = n0 + wn * 64 + j * 16 + l15;
        float v = acc[i][j][r] + bias0[n];
        if (bias1) v += bias1[n];
        C[m * (long)N + n] = f2bf(v);
      }
    }
  }
}

// ---------------- vT[b,n] = sum_k values[b,T-1,k]*W_att[n,k] + b_att[n] (f32 exact) ----
__global__ void vT_kernel(const float* __restrict__ values, const float* __restrict__ W_attT,
                          const float* __restrict__ b_att, float* __restrict__ vT) {
  int b = blockIdx.y;
  int n = blockIdx.x * 256 + threadIdx.x;
  __shared__ float xr[512];
  const float* row = values + ((long)b * 512 + 511) * 512;
  for (int k = threadIdx.x; k < 512; k += 256) xr[k] = row[k];
  __syncthreads();
  float acc = b_att[n];
  for (int k = 0; k < 512; ++k) acc += xr[k] * W_attT[k * 512 + n];
  vT[b * 512 + n] = acc;
}

// ---------------- Dtot[b,ch] = sum_{s=0..510} Deltas[b,s,ch] ----------------
__global__ void dtot_kernel(const float* __restrict__ Deltas, float* __restrict__ Dtot) {
  int idx = blockIdx.x * 256 + threadIdx.x;  // 65536 threads
  int b = idx >> 9, ch = idx & 511;
  const float* p = Deltas + (long)b * 512 * 512 + ch;
  float s = 0.0f;
  for (int t = 0; t < 511; ++t) s += p[(long)t * 512];
  Dtot[idx] = s;
}

// ---------------- logits[b,s] = dot(vT[b,:], values[b,s,:]) (f32) ----------------
__global__ void logits_kernel(const float* __restrict__ values, const float* __restrict__ vT,
                              float* __restrict__ logits) {
  int b = blockIdx.y;
  int wave = threadIdx.x >> 6, lane = threadIdx.x & 63;
  float vreg[8];
  const float* vtb = vT + b * 512;
#pragma unroll
  for (int j = 0; j < 8; ++j) vreg[j] = vtb[lane * 8 + j];
  int s0 = blockIdx.x * 64 + wave * 16;
  for (int si = 0; si < 16; ++si) {
    int s = s0 + si;
    if (s >= 511) break;
    const float* row = values + ((long)b * 512 + s) * 512 + lane * 8;
    float4 a = *(const float4*)row;
    float4 c = *(const float4*)(row + 4);
    float d = a.x * vreg[0] + a.y * vreg[1] + a.z * vreg[2] + a.w * vreg[3] +
              c.x * vreg[4] + c.y * vreg[5] + c.z * vreg[6] + c.w * vreg[7];
#pragma unroll
    for (int off = 32; off; off >>= 1) d += __shfl_xor(d, off);
    if (lane == 0) logits[b * 512 + s] = d;
  }
}

// ---------------- softmax over 511 logits per b (in place -> alpha) ----------------
__global__ void softmax_kernel(float* __restrict__ logits) {
  int b = blockIdx.x, tid = threadIdx.x;  // 256 threads
  __shared__ float wmax[4], wsum[4];
  float v0 = (tid < 511) ? logits[b * 512 + tid] : -1e30f;
  float v1 = (tid + 256 < 511) ? logits[b * 512 + tid + 256] : -1e30f;
  float m = fmaxf(v0, v1);
#pragma unroll
  for (int off = 32; off; off >>= 1) m = fmaxf(m, __shfl_xor(m, off));
  if ((tid & 63) == 0) wmax[tid >> 6] = m;
  __syncthreads();
  m = fmaxf(fmaxf(wmax[0], wmax[1]), fmaxf(wmax[2], wmax[3]));
  float e0 = (tid < 511) ? __expf(v0 - m) : 0.0f;
  float e1 = (tid + 256 < 511) ? __expf(v1 - m) : 0.0f;
  float s = e0 + e1;
#pragma unroll
  for (int off = 32; off; off >>= 1) s += __shfl_xor(s, off);
  if ((tid & 63) == 0) wsum[tid >> 6] = s;
  __syncthreads();
  s = wsum[0] + wsum[1] + wsum[2] + wsum[3];
  float inv = 1.0f / s;
  __syncthreads();
  if (tid < 511) logits[b * 512 + tid] = e0 * inv;
  if (tid + 256 < 511) logits[b * 512 + tid + 256] = e1 * inv;
}

// ---------------- persistent LSTM scan ----------------
// 256 blocks = 8 batch-groups (16 b) x 32 hidden-chunks (16 h). W_hh slice in LDS.
__global__ __launch_bounds__(256, 1)
void scan_kernel(const float* __restrict__ W_hh, const ushort_t* __restrict__ Gx,
                 const float* __restrict__ alpha, const float* __restrict__ Dtot,
                 const float* __restrict__ Deltas, ushort_t* __restrict__ hbuf,
                 int* __restrict__ cnt, float* __restrict__ out) {
  __shared__ __align__(16) ushort_t whh[64 * 512];  // 64KB, swizzled
  __shared__ float gbuf[4][16][16];
  const int tid = threadIdx.x;
  const int bg = blockIdx.x & 7, hc = blockIdx.x >> 3;
  const int b0 = bg * 16, n0 = hc * 16;
  const int lane = tid & 63, wv = tid >> 6;
  const int l15 = lane & 15, l4 = lane >> 4;
  const int eb = tid >> 4, eh = tid & 15;
  const int bglob = b0 + eb, hglob = n0 + eh;

  // load W_hh slice: slice row r = gate(r>>4)*16 + j(r&15) -> global row (r>>4)*512 + n0 + (r&15)
  for (int idx = tid; idx < 64 * 512; idx += 256) {
    int r = idx >> 9, k = idx & 511;
    int grow = (r >> 4) * 512 + n0 + (r & 15);
    float v = W_hh[(long)grow * 512 + k];
    int off = r * 512 + ((((k >> 3) ^ (r & 7)) << 3) | (k & 7));
    whh[off] = f2bf(v);
  }
  float c_state = 0.0f, Cacc = 0.0f;
  float running = Dtot[bglob * 512 + hglob];
  __syncthreads();

  const int brow = wv * 16 + l15;           // W_hh slice row for B-frag (gate=wv, hidden=l15)
  const long gxcol = wv * 512 + n0 + l15;   // Gx column

  for (int t = 0; t < 512; ++t) {
    if (t > 0) {
      if (tid == 0) {
        int g = 0;
        while (__hip_atomic_load(&cnt[bg * 512 + (t - 1)], __ATOMIC_RELAXED,
                                 __HIP_MEMORY_SCOPE_AGENT) < 32) {
          __builtin_amdgcn_s_sleep(1);
          if (++g > (1 << 21)) break;  // safety: never hang
        }
      }
      __syncthreads();
      __threadfence();
    }
    // prefetch independent scalars early (hidden under MFMA)
    float a_t = 0.0f, delta_t = 0.0f;
    if (t < 511) {
      a_t = alpha[bglob * 512 + t];
      delta_t = Deltas[((long)bglob * 512 + (510 - t)) * 512 + hglob];
    }
    float gx[4];
#pragma unroll
    for (int r = 0; r < 4; ++r)
      gx[r] = bf2f(Gx[((long)(b0 + l4 * 4 + r) * 512 + t) * 2048 + gxcol]);

    const ushort_t* hb = hbuf + ((t & 1) * 8 + bg) * (16 * 512);
    s16x8 afr[16], bfr[16];
#pragma unroll
    for (int kk = 0; kk < 16; ++kk) {
      int ks = kk * 32 + l4 * 8;
      afr[kk] = *(const s16x8*)&hb[l15 * 512 + ks];
      int slot = (ks >> 3) ^ (brow & 7);
      bfr[kk] = *(const s16x8*)&whh[brow * 512 + (slot << 3)];
    }
    f32x4 acc = {0.0f, 0.0f, 0.0f, 0.0f};
#pragma unroll
    for (int kk = 0; kk < 16; ++kk)
      acc = __builtin_amdgcn_mfma_f32_16x16x32_bf16(afr[kk], bfr[kk], acc, 0, 0, 0);
#pragma unroll
    for (int r = 0; r < 4; ++r)
      gbuf[wv][l4 * 4 + r][l15] = acc[r] + gx[r];
    __syncthreads();

    float gi = gbuf[0][eb][eh], gf = gbuf[1][eb][eh];
    float gg = gbuf[2][eb][eh], go = gbuf[3][eb][eh];
    float cin = (t == 511) ? Cacc : c_state;
    float cnew = sigmoidf_(gf) * cin + sigmoidf_(gi) * tanhf_(gg);
    float hnew = sigmoidf_(go) * tanhf_(cnew);
    out[((long)bglob * 512 + t) * 512 + hglob] = hnew;
    if (t < 511) {
      c_state = cnew;
      float rl = 1.0f / __logf(2.71828182845904523f + running);
      Cacc += a_t * cnew * rl;
      running -= delta_t;
      ushort_t* hw = hbuf + (((t + 1) & 1) * 8 + bg) * (16 * 512);
      hw[eb * 512 + hglob] = f2bf(hnew);
      __threadfence();
      __syncthreads();
      if (tid == 0)
        __hip_atomic_fetch_add(&cnt[bg * 512 + t], 1, __ATOMIC_RELEASE,
                               __HIP_MEMORY_SCOPE_AGENT);
    }
  }
}

extern "C" void kernel_launch(void* const* d_in, const int* in_sizes, int n_in,
                              void* d_out, int out_size, void* d_ws, size_t ws_size,
                              hipStream_t stream) {
  const float* values = (const float*)d_in[0];
  const float* Deltas = (const float*)d_in[1];
  const float* W_att  = (const float*)d_in[2];
  const float* b_att  = (const float*)d_in[3];
  const float* W_ih   = (const float*)d_in[4];
  const float* W_hh   = (const float*)d_in[5];
  const float* b_ih   = (const float*)d_in[6];
  const float* b_hh   = (const float*)d_in[7];
  float* out = (float*)d_out;

  char* ws = (char*)d_ws;
  size_t off = 0;
  auto alloc = [&](size_t bytes) -> void* {
    void* p = ws + off;
    off += (bytes + 255) & ~(size_t)255;
    return p;
  };
  ushort_t* values_bf = (ushort_t*)alloc(67108864ull);   // (65536,512) bf16
  ushort_t* v_att_bf  = (ushort_t*)alloc(67108864ull);   // (65536,512) bf16
  ushort_t* Gx        = (ushort_t*)alloc(268435456ull);  // (65536,2048) bf16
  ushort_t* W_att_bf  = (ushort_t*)alloc(524288ull);
  ushort_t* W_ih_bf   = (ushort_t*)alloc(2097152ull);
  float*    W_attT    = (float*)alloc(1048576ull);
  float*    vT        = (float*)alloc(262144ull);
  float*    Dtot      = (float*)alloc(262144ull);
  float*    alpha     = (float*)alloc(262144ull);        // logits then alpha, (128,512)
  ushort_t* hbuf      = (ushort_t*)alloc(262144ull);     // (2,8,16,512) bf16
  int*      cnt       = (int*)alloc(16384ull);           // (8,512)

  // zero the scan control state (hbuf + cnt are contiguous)
  hipMemsetAsync(hbuf, 0, 262144ull + 16384ull, stream);

  cast_kernel<<<33554432 / 8 / 256, 256, 0, stream>>>(values, values_bf, 33554432L);
  cast_kernel<<<262144 / 8 / 256, 256, 0, stream>>>(W_att, W_att_bf, 262144L);
  cast_kernel<<<1048576 / 8 / 256, 256, 0, stream>>>(W_ih, W_ih_bf, 1048576L);
  transpose512<<<dim3(16, 16), dim3(32, 8), 0, stream>>>(W_att, W_attT);

  gemm_bt<<<dim3(512, 4), 256, 0, stream>>>(values_bf, W_att_bf, b_att, nullptr,
                                            v_att_bf, 512, 512);
  gemm_bt<<<dim3(512, 16), 256, 0, stream>>>(v_att_bf, W_ih_bf, b_ih, b_hh,
                                             Gx, 2048, 512);

  vT_kernel<<<dim3(2, 128), 256, 0, stream>>>(values, W_attT, b_att, vT);
  dtot_kernel<<<256, 256, 0, stream>>>(Deltas, Dtot);
  logits_kernel<<<dim3(8, 128), 256, 0, stream>>>(values, vT, alpha);
  softmax_kernel<<<128, 256, 0, stream>>>(alpha);

  scan_kernel<<<256, 256, 0, stream>>>(W_hh, Gx, alpha, Dtot, Deltas, hbuf, cnt, out);
}

// Round 2
// 2528.042 us; speedup vs baseline: 8.2552x; 8.2552x over previous
//
#include <hip/hip_runtime.h>
#include <cstdint>

#define DEVI __device__ __forceinline__

typedef unsigned short ushort_t;
typedef __attribute__((ext_vector_type(8))) short s16x8;
typedef __attribute__((ext_vector_type(4))) float f32x4;

DEVI ushort_t f2bf(float f) {
  uint32_t u = __builtin_bit_cast(uint32_t, f);
  u += 0x7fffu + ((u >> 16) & 1u);
  return (ushort_t)(u >> 16);
}
DEVI float bf2f(ushort_t u) {
  uint32_t x = ((uint32_t)u) << 16;
  return __builtin_bit_cast(float, x);
}
DEVI float sigmoidf_(float x) { return 1.0f / (1.0f + __expf(-x)); }
DEVI float tanhf_(float x) {
  float e = __expf(-2.0f * fabsf(x));
  float r = (1.0f - e) / (1.0f + e);
  return copysignf(r, x);
}

// device-scope (MALL-coherent) accessors: bypass L1+L2, no cache flushes.
DEVI void issue_load_h16(s16x8& dst, const ushort_t* p) {
  asm volatile("global_load_dwordx4 %0, %1, off sc0 sc1" : "=v"(dst) : "v"(p));
}
DEVI int load_flag(const int* p) {
  int r;
  asm volatile("global_load_dword %0, %1, off sc0 sc1\n\ts_waitcnt vmcnt(0)"
               : "=v"(r) : "v"(p) : "memory");
  return r;
}
DEVI void store_h(ushort_t* p, uint32_t v) {
  asm volatile("global_store_short %0, %1, off sc0 sc1" :: "v"(p), "v"(v) : "memory");
}
DEVI void store_flag(int* p, int v) {
  asm volatile("global_store_dword %0, %1, off sc0 sc1" :: "v"(p), "v"(v) : "memory");
}
DEVI void wait_vm0() { asm volatile("s_waitcnt vmcnt(0)" ::: "memory"); }

// ---------------- cast f32 -> bf16 (vectorized x8) ----------------
__global__ void cast_kernel(const float* __restrict__ in, ushort_t* __restrict__ out, long n) {
  long i = ((long)blockIdx.x * blockDim.x + threadIdx.x) * 8;
  if (i >= n) return;
  float4 a = *(const float4*)(in + i);
  float4 b = *(const float4*)(in + i + 4);
  union { s16x8 v; ushort_t u[8]; } r;
  r.u[0] = f2bf(a.x); r.u[1] = f2bf(a.y); r.u[2] = f2bf(a.z); r.u[3] = f2bf(a.w);
  r.u[4] = f2bf(b.x); r.u[5] = f2bf(b.y); r.u[6] = f2bf(b.z); r.u[7] = f2bf(b.w);
  *(s16x8*)(out + i) = r.v;
}

// ---------------- 512x512 f32 transpose ----------------
__global__ void transpose512(const float* __restrict__ in, float* __restrict__ out) {
  __shared__ float tile[32][33];
  int bx = blockIdx.x * 32, by = blockIdx.y * 32;
  int tx = threadIdx.x, ty = threadIdx.y;  // 32x8
  for (int i = 0; i < 32; i += 8)
    tile[ty + i][tx] = in[(by + ty + i) * 512 + bx + tx];
  __syncthreads();
  for (int i = 0; i < 32; i += 8)
    out[(bx + ty + i) * 512 + by + tx] = tile[tx][ty + i];
}

// ---------------- bf16 GEMM: C[m,n] = sum_k A[m,k]*B[n,k] + bias ----------------
__global__ __launch_bounds__(256, 2)
void gemm_bt(const ushort_t* __restrict__ A, const ushort_t* __restrict__ B,
             const float* __restrict__ bias0, const float* __restrict__ bias1,
             ushort_t* __restrict__ C, int N, int K) {
  __shared__ __align__(16) ushort_t As[128 * 64];
  __shared__ __align__(16) ushort_t Bs[128 * 64];
  const int tid = threadIdx.x;
  const int lane = tid & 63, wv = tid >> 6;
  const int wm = wv >> 1, wn = wv & 1;
  const int l15 = lane & 15, l4 = lane >> 4;
  const long m0 = (long)blockIdx.x * 128;
  const int n0 = blockIdx.y * 128;
  const int nkt = K / 64;

  f32x4 acc[4][4] = {};

  int soff[4];
#pragma unroll
  for (int i = 0; i < 4; ++i) {
    int c = tid + i * 256;
    int r = c >> 3, ks = c & 7;
    soff[i] = r * 64 + ((ks ^ (r & 7)) << 3);
  }

#pragma unroll
  for (int i = 0; i < 4; ++i) {
    int c = tid + i * 256; int r = c >> 3; int ks = c & 7;
    *(s16x8*)&As[soff[i]] = *(const s16x8*)&A[(m0 + r) * K + ks * 8];
    *(s16x8*)&Bs[soff[i]] = *(const s16x8*)&B[(long)(n0 + r) * K + ks * 8];
  }
  __syncthreads();

  for (int kt = 0; kt < nkt; ++kt) {
    s16x8 ra[4], rb[4];
    const bool more = (kt + 1 < nkt);
    if (more) {
      const long kb = (long)(kt + 1) * 64;
#pragma unroll
      for (int i = 0; i < 4; ++i) {
        int c = tid + i * 256; int r = c >> 3; int ks = c & 7;
        ra[i] = *(const s16x8*)&A[(m0 + r) * K + kb + ks * 8];
        rb[i] = *(const s16x8*)&B[(long)(n0 + r) * K + kb + ks * 8];
      }
    }
#pragma unroll
    for (int kk = 0; kk < 2; ++kk) {
      s16x8 af[4], bfv[4];
      int slot = kk * 4 + l4;
#pragma unroll
      for (int i = 0; i < 4; ++i) {
        int rA = wm * 64 + i * 16 + l15;
        af[i] = *(const s16x8*)&As[rA * 64 + ((slot ^ (rA & 7)) << 3)];
        int rB = wn * 64 + i * 16 + l15;
        bfv[i] = *(const s16x8*)&Bs[rB * 64 + ((slot ^ (rB & 7)) << 3)];
      }
#pragma unroll
      for (int i = 0; i < 4; ++i)
#pragma unroll
        for (int j = 0; j < 4; ++j)
          acc[i][j] = __builtin_amdgcn_mfma_f32_16x16x32_bf16(af[i], bfv[j], acc[i][j], 0, 0, 0);
    }
    __syncthreads();
    if (more) {
#pragma unroll
      for (int i = 0; i < 4; ++i) {
        *(s16x8*)&As[soff[i]] = ra[i];
        *(s16x8*)&Bs[soff[i]] = rb[i];
      }
      __syncthreads();
    }
  }
#pragma unroll
  for (int i = 0; i < 4; ++i) {
#pragma unroll
    for (int j = 0; j < 4; ++j) {
#pragma unroll
      for (int r = 0; r < 4; ++r) {
        long m = m0 + wm * 64 + i * 16 + l4 * 4 + r;
        int n = n0 + wn * 64 + j * 16 + l15;
        float v = acc[i][j][r] + bias0[n];
        if (bias1) v += bias1[n];
        C[m * (long)N + n] = f2bf(v);
      }
    }
  }
}

// ---------------- vT[b,n] = sum_k values[b,T-1,k]*W_att[n,k] + b_att[n] (f32 exact) ----
__global__ void vT_kernel(const float* __restrict__ values, const float* __restrict__ W_attT,
                          const float* __restrict__ b_att, float* __restrict__ vT) {
  int b = blockIdx.y;
  int n = blockIdx.x * 256 + threadIdx.x;
  __shared__ float xr[512];
  const float* row = values + ((long)b * 512 + 511) * 512;
  for (int k = threadIdx.x; k < 512; k += 256) xr[k] = row[k];
  __syncthreads();
  float acc = b_att[n];
  for (int k = 0; k < 512; ++k) acc += xr[k] * W_attT[k * 512 + n];
  vT[b * 512 + n] = acc;
}

// ---------------- Dtot[b,ch] = sum_{s=0..510} Deltas[b,s,ch] ----------------
__global__ void dtot_kernel(const float* __restrict__ Deltas, float* __restrict__ Dtot) {
  int idx = blockIdx.x * 256 + threadIdx.x;
  int b = idx >> 9, ch = idx & 511;
  const float* p = Deltas + (long)b * 512 * 512 + ch;
  float s = 0.0f;
  for (int t = 0; t < 511; ++t) s += p[(long)t * 512];
  Dtot[idx] = s;
}

// ---------------- logits[b,s] = dot(vT[b,:], values[b,s,:]) (f32) ----------------
__global__ void logits_kernel(const float* __restrict__ values, const float* __restrict__ vT,
                              float* __restrict__ logits) {
  int b = blockIdx.y;
  int wave = threadIdx.x >> 6, lane = threadIdx.x & 63;
  float vreg[8];
  const float* vtb = vT + b * 512;
#pragma unroll
  for (int j = 0; j < 8; ++j) vreg[j] = vtb[lane * 8 + j];
  int s0 = blockIdx.x * 64 + wave * 16;
  for (int si = 0; si < 16; ++si) {
    int s = s0 + si;
    if (s >= 511) break;
    const float* row = values + ((long)b * 512 + s) * 512 + lane * 8;
    float4 a = *(const float4*)row;
    float4 c = *(const float4*)(row + 4);
    float d = a.x * vreg[0] + a.y * vreg[1] + a.z * vreg[2] + a.w * vreg[3] +
              c.x * vreg[4] + c.y * vreg[5] + c.z * vreg[6] + c.w * vreg[7];
#pragma unroll
    for (int off = 32; off; off >>= 1) d += __shfl_xor(d, off);
    if (lane == 0) logits[b * 512 + s] = d;
  }
}

// ---------------- softmax over 511 logits per b ----------------
__global__ void softmax_kernel(float* __restrict__ logits) {
  int b = blockIdx.x, tid = threadIdx.x;
  __shared__ float wmax[4], wsum[4];
  float v0 = (tid < 511) ? logits[b * 512 + tid] : -1e30f;
  float v1 = (tid + 256 < 511) ? logits[b * 512 + tid + 256] : -1e30f;
  float m = fmaxf(v0, v1);
#pragma unroll
  for (int off = 32; off; off >>= 1) m = fmaxf(m, __shfl_xor(m, off));
  if ((tid & 63) == 0) wmax[tid >> 6] = m;
  __syncthreads();
  m = fmaxf(fmaxf(wmax[0], wmax[1]), fmaxf(wmax[2], wmax[3]));
  float e0 = (tid < 511) ? __expf(v0 - m) : 0.0f;
  float e1 = (tid + 256 < 511) ? __expf(v1 - m) : 0.0f;
  float s = e0 + e1;
#pragma unroll
  for (int off = 32; off; off >>= 1) s += __shfl_xor(s, off);
  if ((tid & 63) == 0) wsum[tid >> 6] = s;
  __syncthreads();
  s = wsum[0] + wsum[1] + wsum[2] + wsum[3];
  float inv = 1.0f / s;
  __syncthreads();
  if (tid < 511) logits[b * 512 + tid] = e0 * inv;
  if (tid + 256 < 511) logits[b * 512 + tid + 256] = e1 * inv;
}

// ---------------- persistent LSTM scan ----------------
// 256 blocks = 8 batch-groups (16 b) x 32 hidden-chunks (16 h). W_hh slice in LDS.
// Cross-block h handoff via device-scope (sc0 sc1, MALL-coherent) accesses: NO cache flushes.
__global__ __launch_bounds__(256, 1)
void scan_kernel(const float* __restrict__ W_hh, const ushort_t* __restrict__ Gx,
                 const float* __restrict__ alpha, const float* __restrict__ Dtot,
                 const float* __restrict__ Deltas, ushort_t* __restrict__ hbuf,
                 int* __restrict__ flags, float* __restrict__ out) {
  __shared__ __align__(16) ushort_t whh[64 * 512];  // 64KB, swizzled
  __shared__ float gbuf[4][16][17];                 // padded: no 4-way bank conflict
  const int tid = threadIdx.x;
  const int bg = blockIdx.x & 7, hc = blockIdx.x >> 3;
  const int b0 = bg * 16, n0 = hc * 16;
  const int lane = tid & 63, wv = tid >> 6;
  const int l15 = lane & 15, l4 = lane >> 4;
  const int eb = tid >> 4, eh = tid & 15;
  const int bglob = b0 + eb, hglob = n0 + eh;

  // load W_hh slice into LDS (bf16, XOR-swizzled rows)
  for (int idx = tid; idx < 64 * 512; idx += 256) {
    int r = idx >> 9, k = idx & 511;
    int grow = (r >> 4) * 512 + n0 + (r & 15);
    float v = W_hh[(long)grow * 512 + k];
    int off = r * 512 + ((((k >> 3) ^ (r & 7)) << 3) | (k & 7));
    whh[off] = f2bf(v);
  }
  float c_state = 0.0f, Cacc = 0.0f;
  float running = Dtot[bglob * 512 + hglob];
  __syncthreads();

  // hoist loop-invariant W_hh B-fragments into registers (read LDS once)
  const int brow = wv * 16 + l15;
  s16x8 bfr[16];
#pragma unroll
  for (int kk = 0; kk < 16; ++kk) {
    int slot = (kk * 4 + l4) ^ (brow & 7);
    bfr[kk] = *(const s16x8*)&whh[brow * 512 + (slot << 3)];
  }
  const long gxcol = wv * 512 + n0 + l15;

  for (int t = 0; t < 512; ++t) {
    // prefetch step-t inputs (plain cached loads, in flight during the poll)
    float a_t = 0.0f, delta_t = 0.0f;
    if (t < 511) {
      a_t = alpha[bglob * 512 + t];
      delta_t = Deltas[((long)bglob * 512 + (510 - t)) * 512 + hglob];
    }
    float gx[4];
#pragma unroll
    for (int r = 0; r < 4; ++r)
      gx[r] = bf2f(Gx[((long)(b0 + l4 * 4 + r) * 512 + t) * 2048 + gxcol]);

    if (t > 0) {
      if (wv == 0) {
        const int* fp = flags + ((long)bg * 512 + (t - 1)) * 32 + (lane & 31);
        int g = 0;
        while (!__all(load_flag(fp) != 0)) {
          __builtin_amdgcn_s_sleep(1);
          if (++g > (1 << 20)) break;  // safety: never hang
        }
      }
      __syncthreads();
    }

    // read h(t) fragments from MALL (bypass stale L1/L2)
    const ushort_t* hb = hbuf + ((t & 1) * 8 + bg) * (16 * 512);
    s16x8 afr[16];
#pragma unroll
    for (int kk = 0; kk < 16; ++kk)
      issue_load_h16(afr[kk], hb + l15 * 512 + kk * 32 + l4 * 8);
    wait_vm0();
    __builtin_amdgcn_sched_barrier(0);

    f32x4 acc = {0.0f, 0.0f, 0.0f, 0.0f};
#pragma unroll
    for (int kk = 0; kk < 16; ++kk)
      acc = __builtin_amdgcn_mfma_f32_16x16x32_bf16(afr[kk], bfr[kk], acc, 0, 0, 0);
#pragma unroll
    for (int r = 0; r < 4; ++r)
      gbuf[wv][l4 * 4 + r][l15] = acc[r] + gx[r];
    __syncthreads();

    float gi = gbuf[0][eb][eh], gf = gbuf[1][eb][eh];
    float gg = gbuf[2][eb][eh], go = gbuf[3][eb][eh];
    float cin = (t == 511) ? Cacc : c_state;
    float cnew = sigmoidf_(gf) * cin + sigmoidf_(gi) * tanhf_(gg);
    float hnew = sigmoidf_(go) * tanhf_(cnew);
    out[((long)bglob * 512 + t) * 512 + hglob] = hnew;
    if (t < 511) {
      c_state = cnew;
      float rl = 1.0f / __logf(2.71828182845904523f + running);
      Cacc += a_t * cnew * rl;
      running -= delta_t;
      ushort_t* hw = hbuf + (((t + 1) & 1) * 8 + bg) * (16 * 512);
      store_h(hw + eb * 512 + hglob, (uint32_t)f2bf(hnew));
      wait_vm0();            // this thread's h store is at the coherence point
      __syncthreads();       // all threads in block done storing
      if (tid == 0)
        store_flag(flags + ((long)bg * 512 + t) * 32 + hc, 1);
    }
  }
}

extern "C" void kernel_launch(void* const* d_in, const int* in_sizes, int n_in,
                              void* d_out, int out_size, void* d_ws, size_t ws_size,
                              hipStream_t stream) {
  const float* values = (const float*)d_in[0];
  const float* Deltas = (const float*)d_in[1];
  const float* W_att  = (const float*)d_in[2];
  const float* b_att  = (const float*)d_in[3];
  const float* W_ih   = (const float*)d_in[4];
  const float* W_hh   = (const float*)d_in[5];
  const float* b_ih   = (const float*)d_in[6];
  const float* b_hh   = (const float*)d_in[7];
  float* out = (float*)d_out;

  char* ws = (char*)d_ws;
  size_t off = 0;
  auto alloc = [&](size_t bytes) -> void* {
    void* p = ws + off;
    off += (bytes + 255) & ~(size_t)255;
    return p;
  };
  ushort_t* values_bf = (ushort_t*)alloc(67108864ull);   // (65536,512) bf16
  ushort_t* v_att_bf  = (ushort_t*)alloc(67108864ull);   // (65536,512) bf16
  ushort_t* Gx        = (ushort_t*)alloc(268435456ull);  // (65536,2048) bf16
  ushort_t* W_att_bf  = (ushort_t*)alloc(524288ull);
  ushort_t* W_ih_bf   = (ushort_t*)alloc(2097152ull);
  float*    W_attT    = (float*)alloc(1048576ull);
  float*    vT        = (float*)alloc(262144ull);
  float*    Dtot      = (float*)alloc(262144ull);
  float*    alpha     = (float*)alloc(262144ull);        // logits then alpha
  ushort_t* hbuf      = (ushort_t*)alloc(262144ull);     // (2,8,16,512) bf16
  int*      flags     = (int*)alloc(524288ull);          // (8,512,32)

  hipMemsetAsync(hbuf, 0, 262144ull + 524288ull, stream);

  cast_kernel<<<33554432 / 8 / 256, 256, 0, stream>>>(values, values_bf, 33554432L);
  cast_kernel<<<262144 / 8 / 256, 256, 0, stream>>>(W_att, W_att_bf, 262144L);
  cast_kernel<<<1048576 / 8 / 256, 256, 0, stream>>>(W_ih, W_ih_bf, 1048576L);
  transpose512<<<dim3(16, 16), dim3(32, 8), 0, stream>>>(W_att, W_attT);

  gemm_bt<<<dim3(512, 4), 256, 0, stream>>>(values_bf, W_att_bf, b_att, nullptr,
                                            v_att_bf, 512, 512);
  gemm_bt<<<dim3(512, 16), 256, 0, stream>>>(v_att_bf, W_ih_bf, b_ih, b_hh,
                                             Gx, 2048, 512);

  vT_kernel<<<dim3(2, 128), 256, 0, stream>>>(values, W_attT, b_att, vT);
  dtot_kernel<<<256, 256, 0, stream>>>(Deltas, Dtot);
  logits_kernel<<<dim3(8, 128), 256, 0, stream>>>(values, vT, alpha);
  softmax_kernel<<<128, 256, 0, stream>>>(alpha);

  scan_kernel<<<256, 256, 0, stream>>>(W_hh, Gx, alpha, Dtot, Deltas, hbuf, flags, out);
}

// Round 3
// 2285.392 us; speedup vs baseline: 9.1317x; 1.1062x over previous
//
#include <hip/hip_runtime.h>
#include <cstdint>

#define DEVI __device__ __forceinline__

typedef unsigned short ushort_t;
typedef __attribute__((ext_vector_type(8))) short s16x8;
typedef __attribute__((ext_vector_type(4))) int i32x4;
typedef __attribute__((ext_vector_type(4))) float f32x4;

DEVI ushort_t f2bf(float f) {
  uint32_t u = __builtin_bit_cast(uint32_t, f);
  u += 0x7fffu + ((u >> 16) & 1u);
  return (ushort_t)(u >> 16);
}
DEVI float bf2f(ushort_t u) {
  uint32_t x = ((uint32_t)u) << 16;
  return __builtin_bit_cast(float, x);
}
DEVI float sigmoidf_(float x) { return 1.0f / (1.0f + __expf(-x)); }
DEVI float tanhf_(float x) {
  float e = __expf(-2.0f * fabsf(x));
  float r = (1.0f - e) / (1.0f + e);
  return copysignf(r, x);
}

// device-scope (MALL-coherent) accessors: bypass L1+L2, no cache maintenance.
DEVI void load_tag16(i32x4& dst, const uint32_t* p) {
  asm volatile("global_load_dwordx4 %0, %1, off sc0 sc1" : "=v"(dst) : "v"(p));
}
DEVI void store_tagged(uint32_t* p, uint32_t v) {
  asm volatile("global_store_dword %0, %1, off sc0 sc1" :: "v"(p), "v"(v) : "memory");
}
DEVI void wait_vm0() { asm volatile("s_waitcnt vmcnt(0)" ::: "memory"); }

// ---------------- cast f32 -> bf16 (vectorized x8) ----------------
__global__ void cast_kernel(const float* __restrict__ in, ushort_t* __restrict__ out, long n) {
  long i = ((long)blockIdx.x * blockDim.x + threadIdx.x) * 8;
  if (i >= n) return;
  float4 a = *(const float4*)(in + i);
  float4 b = *(const float4*)(in + i + 4);
  union { s16x8 v; ushort_t u[8]; } r;
  r.u[0] = f2bf(a.x); r.u[1] = f2bf(a.y); r.u[2] = f2bf(a.z); r.u[3] = f2bf(a.w);
  r.u[4] = f2bf(b.x); r.u[5] = f2bf(b.y); r.u[6] = f2bf(b.z); r.u[7] = f2bf(b.w);
  *(s16x8*)(out + i) = r.v;
}

// ---------------- 512x512 f32 transpose ----------------
__global__ void transpose512(const float* __restrict__ in, float* __restrict__ out) {
  __shared__ float tile[32][33];
  int bx = blockIdx.x * 32, by = blockIdx.y * 32;
  int tx = threadIdx.x, ty = threadIdx.y;  // 32x8
  for (int i = 0; i < 32; i += 8)
    tile[ty + i][tx] = in[(by + ty + i) * 512 + bx + tx];
  __syncthreads();
  for (int i = 0; i < 32; i += 8)
    out[(bx + ty + i) * 512 + by + tx] = tile[tx][ty + i];
}

// ---------------- bf16 GEMM: C[m,n] = sum_k A[m,k]*B[n,k] + bias ----------------
__global__ __launch_bounds__(256, 2)
void gemm_bt(const ushort_t* __restrict__ A, const ushort_t* __restrict__ B,
             const float* __restrict__ bias0, const float* __restrict__ bias1,
             ushort_t* __restrict__ C, int N, int K) {
  __shared__ __align__(16) ushort_t As[128 * 64];
  __shared__ __align__(16) ushort_t Bs[128 * 64];
  const int tid = threadIdx.x;
  const int lane = tid & 63, wv = tid >> 6;
  const int wm = wv >> 1, wn = wv & 1;
  const int l15 = lane & 15, l4 = lane >> 4;
  const long m0 = (long)blockIdx.x * 128;
  const int n0 = blockIdx.y * 128;
  const int nkt = K / 64;

  f32x4 acc[4][4] = {};

  int soff[4];
#pragma unroll
  for (int i = 0; i < 4; ++i) {
    int c = tid + i * 256;
    int r = c >> 3, ks = c & 7;
    soff[i] = r * 64 + ((ks ^ (r & 7)) << 3);
  }

#pragma unroll
  for (int i = 0; i < 4; ++i) {
    int c = tid + i * 256; int r = c >> 3; int ks = c & 7;
    *(s16x8*)&As[soff[i]] = *(const s16x8*)&A[(m0 + r) * K + ks * 8];
    *(s16x8*)&Bs[soff[i]] = *(const s16x8*)&B[(long)(n0 + r) * K + ks * 8];
  }
  __syncthreads();

  for (int kt = 0; kt < nkt; ++kt) {
    s16x8 ra[4], rb[4];
    const bool more = (kt + 1 < nkt);
    if (more) {
      const long kb = (long)(kt + 1) * 64;
#pragma unroll
      for (int i = 0; i < 4; ++i) {
        int c = tid + i * 256; int r = c >> 3; int ks = c & 7;
        ra[i] = *(const s16x8*)&A[(m0 + r) * K + kb + ks * 8];
        rb[i] = *(const s16x8*)&B[(long)(n0 + r) * K + kb + ks * 8];
      }
    }
#pragma unroll
    for (int kk = 0; kk < 2; ++kk) {
      s16x8 af[4], bfv[4];
      int slot = kk * 4 + l4;
#pragma unroll
      for (int i = 0; i < 4; ++i) {
        int rA = wm * 64 + i * 16 + l15;
        af[i] = *(const s16x8*)&As[rA * 64 + ((slot ^ (rA & 7)) << 3)];
        int rB = wn * 64 + i * 16 + l15;
        bfv[i] = *(const s16x8*)&Bs[rB * 64 + ((slot ^ (rB & 7)) << 3)];
      }
#pragma unroll
      for (int i = 0; i < 4; ++i)
#pragma unroll
        for (int j = 0; j < 4; ++j)
          acc[i][j] = __builtin_amdgcn_mfma_f32_16x16x32_bf16(af[i], bfv[j], acc[i][j], 0, 0, 0);
    }
    __syncthreads();
    if (more) {
#pragma unroll
      for (int i = 0; i < 4; ++i) {
        *(s16x8*)&As[soff[i]] = ra[i];
        *(s16x8*)&Bs[soff[i]] = rb[i];
      }
      __syncthreads();
    }
  }
#pragma unroll
  for (int i = 0; i < 4; ++i) {
#pragma unroll
    for (int j = 0; j < 4; ++j) {
#pragma unroll
      for (int r = 0; r < 4; ++r) {
        long m = m0 + wm * 64 + i * 16 + l4 * 4 + r;
        int n = n0 + wn * 64 + j * 16 + l15;
        float v = acc[i][j][r];
        if (bias0) v += bias0[n];
        if (bias1) v += bias1[n];
        C[m * (long)N + n] = f2bf(v);
      }
    }
  }
}

// ---------------- bias_c[n] = b_ih[n] + b_hh[n] + dot(W_ih[n,:], b_att) ----------------
__global__ void bias_combo_kernel(const float* __restrict__ W_ih, const float* __restrict__ b_att,
                                  const float* __restrict__ b_ih, const float* __restrict__ b_hh,
                                  float* __restrict__ bc) {
  int n = blockIdx.x * 256 + threadIdx.x;  // 2048
  __shared__ float ba[512];
  for (int k = threadIdx.x; k < 512; k += 256) ba[k] = b_att[k];
  __syncthreads();
  float s = b_ih[n] + b_hh[n];
  const float* row = W_ih + (long)n * 512;
  for (int k = 0; k < 512; ++k) s += row[k] * ba[k];
  bc[n] = s;
}

// ---------------- vT[b,n] = sum_k values[b,T-1,k]*W_att[n,k] + b_att[n] (f32 exact) ----
__global__ void vT_kernel(const float* __restrict__ values, const float* __restrict__ W_attT,
                          const float* __restrict__ b_att, float* __restrict__ vT) {
  int b = blockIdx.y;
  int n = blockIdx.x * 256 + threadIdx.x;
  __shared__ float xr[512];
  const float* row = values + ((long)b * 512 + 511) * 512;
  for (int k = threadIdx.x; k < 512; k += 256) xr[k] = row[k];
  __syncthreads();
  float acc = b_att[n];
  for (int k = 0; k < 512; ++k) acc += xr[k] * W_attT[k * 512 + n];
  vT[b * 512 + n] = acc;
}

// ---------------- Dtot[b,ch] = sum_{s=0..510} Deltas[b,s,ch] ----------------
__global__ void dtot_kernel(const float* __restrict__ Deltas, float* __restrict__ Dtot) {
  int idx = blockIdx.x * 256 + threadIdx.x;
  int b = idx >> 9, ch = idx & 511;
  const float* p = Deltas + (long)b * 512 * 512 + ch;
  float s = 0.0f;
  for (int t = 0; t < 511; ++t) s += p[(long)t * 512];
  Dtot[idx] = s;
}

// ---------------- logits[b,s] = dot(vT[b,:], values[b,s,:]) (f32) ----------------
__global__ void logits_kernel(const float* __restrict__ values, const float* __restrict__ vT,
                              float* __restrict__ logits) {
  int b = blockIdx.y;
  int wave = threadIdx.x >> 6, lane = threadIdx.x & 63;
  float vreg[8];
  const float* vtb = vT + b * 512;
#pragma unroll
  for (int j = 0; j < 8; ++j) vreg[j] = vtb[lane * 8 + j];
  int s0 = blockIdx.x * 64 + wave * 16;
  for (int si = 0; si < 16; ++si) {
    int s = s0 + si;
    if (s >= 511) break;
    const float* row = values + ((long)b * 512 + s) * 512 + lane * 8;
    float4 a = *(const float4*)row;
    float4 c = *(const float4*)(row + 4);
    float d = a.x * vreg[0] + a.y * vreg[1] + a.z * vreg[2] + a.w * vreg[3] +
              c.x * vreg[4] + c.y * vreg[5] + c.z * vreg[6] + c.w * vreg[7];
#pragma unroll
    for (int off = 32; off; off >>= 1) d += __shfl_xor(d, off);
    if (lane == 0) logits[b * 512 + s] = d;
  }
}

// ---------------- softmax over 511 logits per b ----------------
__global__ void softmax_kernel(float* __restrict__ logits) {
  int b = blockIdx.x, tid = threadIdx.x;
  __shared__ float wmax[4], wsum[4];
  float v0 = (tid < 511) ? logits[b * 512 + tid] : -1e30f;
  float v1 = (tid + 256 < 511) ? logits[b * 512 + tid + 256] : -1e30f;
  float m = fmaxf(v0, v1);
#pragma unroll
  for (int off = 32; off; off >>= 1) m = fmaxf(m, __shfl_xor(m, off));
  if ((tid & 63) == 0) wmax[tid >> 6] = m;
  __syncthreads();
  m = fmaxf(fmaxf(wmax[0], wmax[1]), fmaxf(wmax[2], wmax[3]));
  float e0 = (tid < 511) ? __expf(v0 - m) : 0.0f;
  float e1 = (tid + 256 < 511) ? __expf(v1 - m) : 0.0f;
  float s = e0 + e1;
#pragma unroll
  for (int off = 32; off; off >>= 1) s += __shfl_xor(s, off);
  if ((tid & 63) == 0) wsum[tid >> 6] = s;
  __syncthreads();
  s = wsum[0] + wsum[1] + wsum[2] + wsum[3];
  float inv = 1.0f / s;
  __syncthreads();
  if (tid < 511) logits[b * 512 + tid] = e0 * inv;
  if (tid + 256 < 511) logits[b * 512 + tid + 256] = e1 * inv;
}

// ---------------- persistent LSTM scan, tagged single-round-trip handoff ----------------
// 256 blocks = 8 batch-groups (16 b) x 32 hidden-chunks (16 h). W_hh slice in LDS.
// h handoff: 32-bit words (tag<<16)|bf16(h), device-scope; consumer polls data directly.
// K split across 4 waves (128 each, all 4 gates), partials reduced via LDS (parity dbuf).
__global__ __launch_bounds__(256, 1)
void scan_kernel(const float* __restrict__ W_hh, const ushort_t* __restrict__ Gx,
                 const float* __restrict__ alpha, const float* __restrict__ Dtot,
                 const float* __restrict__ Deltas, uint32_t* __restrict__ hbuf32,
                 float* __restrict__ out) {
  __shared__ __align__(16) ushort_t whh[64 * 512];   // 64KB, XOR-swizzled
  __shared__ float gbuf[2][4][4][16][16];            // [parity][wave][gate][row][col] 32KB
  const int tid = threadIdx.x;
  const int bg = blockIdx.x & 7, hc = blockIdx.x >> 3;
  const int b0 = bg * 16, n0 = hc * 16;
  const int lane = tid & 63, wv = tid >> 6;
  const int l15 = lane & 15, l4 = lane >> 4;
  const int eb = tid >> 4, eh = tid & 15;
  const int bglob = b0 + eb, hglob = n0 + eh;

  // load W_hh slice into LDS (bf16, XOR-swizzled rows); slice row r = gate(r>>4)*16 + (r&15)
  for (int idx = tid; idx < 64 * 512; idx += 256) {
    int r = idx >> 9, k = idx & 511;
    int grow = (r >> 4) * 512 + n0 + (r & 15);
    float v = W_hh[(long)grow * 512 + k];
    int off = r * 512 + ((((k >> 3) ^ (r & 7)) << 3) | (k & 7));
    whh[off] = f2bf(v);
  }
  float c_state = 0.0f, Cacc = 0.0f;
  float running = Dtot[bglob * 512 + hglob];
  __syncthreads();

  // hoist loop-invariant W_hh B-fragments: bfr[gate][kk4], k = wv*128 + kk4*32 + l4*8
  s16x8 bfr[4][4];
#pragma unroll
  for (int g = 0; g < 4; ++g) {
    const int brow = g * 16 + l15;
#pragma unroll
    for (int kk4 = 0; kk4 < 4; ++kk4) {
      int ks = wv * 128 + kk4 * 32 + l4 * 8;
      int slot = (ks >> 3) ^ (brow & 7);
      bfr[g][kk4] = *(const s16x8*)&whh[brow * 512 + (slot << 3)];
    }
  }

  for (int t = 0; t < 512; ++t) {
    // prefetch step-t inputs (plain cached loads, hidden under the poll)
    float a_t = 0.0f, delta_t = 0.0f;
    if (t < 511) {
      a_t = alpha[bglob * 512 + t];
      delta_t = Deltas[((long)bglob * 512 + (510 - t)) * 512 + hglob];
    }
    float gxv[4];
#pragma unroll
    for (int g = 0; g < 4; ++g)
      gxv[g] = bf2f(Gx[((long)bglob * 512 + t) * 2048 + g * 512 + hglob]);

    // poll + load h(t): self-validating tagged words, single round trip
    const uint32_t* hb = hbuf32 + ((t & 1) * 8 + bg) * 8192 + l15 * 512 + wv * 128 + l4 * 8;
    const uint32_t expect = (uint32_t)t << 16;
    i32x4 q[8];
    int guard = 0;
    for (;;) {
#pragma unroll
      for (int kk4 = 0; kk4 < 4; ++kk4) {
        load_tag16(q[kk4 * 2], hb + kk4 * 32);
        load_tag16(q[kk4 * 2 + 1], hb + kk4 * 32 + 4);
      }
      wait_vm0();
      __builtin_amdgcn_sched_barrier(0);
      uint32_t bad = 0;
#pragma unroll
      for (int i = 0; i < 8; ++i) {
        bad |= (uint32_t)q[i][0] ^ expect;
        bad |= (uint32_t)q[i][1] ^ expect;
        bad |= (uint32_t)q[i][2] ^ expect;
        bad |= (uint32_t)q[i][3] ^ expect;
      }
      if (!__any((bad & 0xffff0000u) != 0)) break;
      __builtin_amdgcn_s_sleep(1);
      if (++guard > (1 << 16)) break;  // safety: never hang
    }
    // unpack payload (low 16 bits) into bf16 A-fragments
    s16x8 afr[4];
#pragma unroll
    for (int kk4 = 0; kk4 < 4; ++kk4) {
#pragma unroll
      for (int j = 0; j < 4; ++j) {
        afr[kk4][j]     = (short)((uint32_t)q[kk4 * 2][j] & 0xffffu);
        afr[kk4][j + 4] = (short)((uint32_t)q[kk4 * 2 + 1][j] & 0xffffu);
      }
    }
    // partial matvec: this wave's k-slice, all 4 gates
    f32x4 acc[4] = {};
#pragma unroll
    for (int kk4 = 0; kk4 < 4; ++kk4)
#pragma unroll
      for (int g = 0; g < 4; ++g)
        acc[g] = __builtin_amdgcn_mfma_f32_16x16x32_bf16(afr[kk4], bfr[g][kk4], acc[g], 0, 0, 0);

    const int p = t & 1;
#pragma unroll
    for (int g = 0; g < 4; ++g)
#pragma unroll
      for (int r = 0; r < 4; ++r)
        gbuf[p][wv][g][l4 * 4 + r][l15] = acc[g][r];
    __syncthreads();

    float gate[4];
#pragma unroll
    for (int g = 0; g < 4; ++g)
      gate[g] = gbuf[p][0][g][eb][eh] + gbuf[p][1][g][eb][eh] +
                gbuf[p][2][g][eb][eh] + gbuf[p][3][g][eb][eh] + gxv[g];

    float cin = (t == 511) ? Cacc : c_state;
    float cnew = sigmoidf_(gate[1]) * cin + sigmoidf_(gate[0]) * tanhf_(gate[2]);
    float hnew = sigmoidf_(gate[3]) * tanhf_(cnew);
    out[((long)bglob * 512 + t) * 512 + hglob] = hnew;
    if (t < 511) {
      c_state = cnew;
      float rl = 1.0f / __logf(2.71828182845904523f + running);
      Cacc += a_t * cnew * rl;
      running -= delta_t;
      uint32_t w = ((uint32_t)(t + 1) << 16) | (uint32_t)f2bf(hnew);
      store_tagged(hbuf32 + (((t + 1) & 1) * 8 + bg) * 8192 + eb * 512 + hglob, w);
    }
  }
}

extern "C" void kernel_launch(void* const* d_in, const int* in_sizes, int n_in,
                              void* d_out, int out_size, void* d_ws, size_t ws_size,
                              hipStream_t stream) {
  const float* values = (const float*)d_in[0];
  const float* Deltas = (const float*)d_in[1];
  const float* W_att  = (const float*)d_in[2];
  const float* b_att  = (const float*)d_in[3];
  const float* W_ih   = (const float*)d_in[4];
  const float* W_hh   = (const float*)d_in[5];
  const float* b_ih   = (const float*)d_in[6];
  const float* b_hh   = (const float*)d_in[7];
  float* out = (float*)d_out;

  char* ws = (char*)d_ws;
  size_t off = 0;
  auto alloc = [&](size_t bytes) -> void* {
    void* p = ws + off;
    off += (bytes + 255) & ~(size_t)255;
    return p;
  };
  ushort_t* values_bf = (ushort_t*)alloc(67108864ull);   // (65536,512) bf16
  ushort_t* Gx        = (ushort_t*)alloc(268435456ull);  // (65536,2048) bf16
  ushort_t* W_ih_bf   = (ushort_t*)alloc(2097152ull);    // (2048,512) bf16
  ushort_t* Wc_bf     = (ushort_t*)alloc(2097152ull);    // (2048,512) bf16 = W_ih@W_att
  float*    W_attT    = (float*)alloc(1048576ull);
  ushort_t* W_attT_bf = (ushort_t*)alloc(524288ull);
  float*    vT        = (float*)alloc(262144ull);
  float*    Dtot      = (float*)alloc(262144ull);
  float*    alpha     = (float*)alloc(262144ull);        // logits then alpha
  float*    bias_c    = (float*)alloc(8192ull);          // (2048,)
  uint32_t* hbuf32    = (uint32_t*)alloc(524288ull);     // (2,8,16,512) tagged dwords

  hipMemsetAsync(hbuf32, 0, 524288ull, stream);

  cast_kernel<<<33554432 / 8 / 256, 256, 0, stream>>>(values, values_bf, 33554432L);
  cast_kernel<<<1048576 / 8 / 256, 256, 0, stream>>>(W_ih, W_ih_bf, 1048576L);
  transpose512<<<dim3(16, 16), dim3(32, 8), 0, stream>>>(W_att, W_attT);
  cast_kernel<<<262144 / 8 / 256, 256, 0, stream>>>(W_attT, W_attT_bf, 262144L);

  // Wc = W_ih @ W_att  (B operand = W_att^T rows)
  gemm_bt<<<dim3(16, 4), 256, 0, stream>>>(W_ih_bf, W_attT_bf, nullptr, nullptr,
                                           Wc_bf, 512, 512);
  bias_combo_kernel<<<8, 256, 0, stream>>>(W_ih, b_att, b_ih, b_hh, bias_c);

  // Gx = values @ Wc^T + bias_c   (folded: == (values@W_att^T+b_att)@W_ih^T + b_ih + b_hh)
  gemm_bt<<<dim3(512, 16), 256, 0, stream>>>(values_bf, Wc_bf, bias_c, nullptr,
                                             Gx, 2048, 512);

  vT_kernel<<<dim3(2, 128), 256, 0, stream>>>(values, W_attT, b_att, vT);
  dtot_kernel<<<256, 256, 0, stream>>>(Deltas, Dtot);
  logits_kernel<<<dim3(8, 128), 256, 0, stream>>>(values, vT, alpha);
  softmax_kernel<<<128, 256, 0, stream>>>(alpha);

  scan_kernel<<<256, 256, 0, stream>>>(W_hh, Gx, alpha, Dtot, Deltas, hbuf32, out);
}